// Round 6
// baseline (392.120 us; speedup 1.0000x reference)
//
#include <hip/hip_runtime.h>

// Problem constants (match reference)
#define BGRAPH 64
#define NNODE  128
#define EMB    16
#define OUTF   64
#define EREAL  65536
#define TOTAL  (BGRAPH * NNODE * NNODE)   // 1048576 pairs

// Native clang vector type.
typedef float floatx4 __attribute__((ext_vector_type(4)));

// Edge binning: per-pair counter + up to 8 edge-id slots in workspace.
// P(any pair has >8 duplicate edges) ~ 1.5e-8 for 1024 random edges per
// 16384-pair graph.
#define SLOT_CAP 8

// ---------------------------------------------------------------------------
// Kernel A: zero the per-pair counters AND write the closed-form coalesced
// index output, one float4 quad of each per thread. For a 4-aligned p-quad
// the src value (g*128 + rem/128) is constant (splat); dst is consecutive.
__global__ __launch_bounds__(256) void init_kernel(
    uint4* __restrict__ cnt4,        // [TOTAL/4]
    float* __restrict__ out_idx)     // [2*TOTAL]
{
    int t  = blockIdx.x * 256 + threadIdx.x;   // [0, TOTAL/4)
    cnt4[t] = make_uint4(0u, 0u, 0u, 0u);

    int p0  = t * 4;
    int g   = p0 >> 14;            // / (N*N)
    int rem = p0 & 16383;          // % (N*N)
    float sv = (float)(g * NNODE + (rem >> 7));       // same for all 4
    float dbase = (float)(g * NNODE + (rem & 127));
    floatx4 s = {sv, sv, sv, sv};
    floatx4 d = {dbase, dbase + 1.f, dbase + 2.f, dbase + 3.f};
    *(floatx4*)(out_idx + p0)          = s;
    *(floatx4*)(out_idx + TOTAL + p0)  = d;
}

// ---------------------------------------------------------------------------
// Kernel B: bin edges by flat pair id (65536 atomics instead of 4.2M).
__global__ __launch_bounds__(256) void bin_kernel(
    const int* __restrict__ edge_index,   // [2, EREAL] flat: src then dst
    unsigned* __restrict__ cnt,           // [TOTAL]
    unsigned* __restrict__ slots)         // [TOTAL * SLOT_CAP]
{
    int e = blockIdx.x * 256 + threadIdx.x;
    int src = edge_index[e];
    int dst = edge_index[EREAL + e];
    int fid = src * NNODE + (dst & (NNODE - 1));   // src*128 + dst%128
    unsigned pos = atomicAdd(&cnt[fid], 1u);
    if (pos < SLOT_CAP)
        slots[(size_t)fid * SLOT_CAP + pos] = (unsigned)e;
}

// ---------------------------------------------------------------------------
// Kernel C: out_val[p][o] = gm_val[p][:] @ W[o][:]  (+ binned edge attrs).
//
// Persistent double-buffered LDS version. v5 (one chunk per block) fixed the
// load-redundancy cap (192 -> ~99 us) but left the 16 KB stage latency
// exposed on every block and used NT stores (unproven BW path; the harness
// fill kernel reaches 6.3 TB/s with REGULAR stores). Here:
//   - 1024 blocks (4/CU, all resident), each owns 4 contiguous 256-row
//     chunks; chunk j+1's global loads are issued right after the barrier
//     so their latency hides under chunk j's 16-step compute.
//   - double-buffered LDS, ONE barrier per chunk. Proof: ds_write(j+1)
//     targets buf[(j+1)&1], last read during compute(j-1); every thread's
//     compute(j-1) precedes barrier(j) and every thread's ds_write(j+1)
//     follows barrier(j) in program order, so the barrier separates them.
//   - regular (cached) stores instead of NT.
//
// Geometry: 256 threads = 16 groups of 16 lanes. Group g, step s handles
// row base + g + 16*s; a wave's 4 groups cover 4 consecutive rows, so each
// store wave-instr writes 1 KB contiguous. Per-group edge counts are
// batch-loaded (lane l holds cnt for step l) and distributed via shfl.
#define CHUNK 256
#define NBLOCKS 1024
#define NCHUNK (TOTAL / (CHUNK * NBLOCKS))   // = 4 chunks per block

template <bool FUSED>
__global__ __launch_bounds__(256) void gemm_lds_kernel(
    const float* __restrict__ gm_val,
    const float* __restrict__ W,
    const unsigned* __restrict__ cnt,
    const unsigned* __restrict__ slots,
    const float* __restrict__ edge_attr,
    float* __restrict__ out_val)
{
    __shared__ floatx4 lds[2][CHUNK * 4];         // 2 x 16 KB
    const int tid  = threadIdx.x;
    const int oq   = tid & 15;                    // lane within group
    const int grp  = tid >> 4;                    // 0..15
    const int chunk0 = blockIdx.x * NCHUNK;       // 4 contiguous chunks

    // Prologue: issue chunk 0's loads (4 dense float4 per thread).
    const floatx4* src = (const floatx4*)gm_val + (size_t)chunk0 * CHUNK * 4;
    floatx4 s0 = src[tid];
    floatx4 s1 = src[tid + 256];
    floatx4 s2 = src[tid + 512];
    floatx4 s3 = src[tid + 768];
    unsigned cv = 0;
    if (FUSED) cv = cnt[chunk0 * CHUNK + grp + 16 * oq];

    // W slice for this lane's output quad (64 floats, L2-resident
    // broadcast), issued after the HBM loads are already in flight.
    float w[4][16];
    const floatx4* W4 = (const floatx4*)W + oq * 16;
    #pragma unroll
    for (int j = 0; j < 4; ++j) {
        #pragma unroll
        for (int q = 0; q < 4; ++q) {
            floatx4 t = W4[j * 4 + q];
            w[j][q * 4 + 0] = t.x;
            w[j][q * 4 + 1] = t.y;
            w[j][q * 4 + 2] = t.z;
            w[j][q * 4 + 3] = t.w;
        }
    }

    #pragma unroll
    for (int j = 0; j < NCHUNK; ++j) {
        floatx4* buf = lds[j & 1];
        buf[tid]       = s0;
        buf[tid + 256] = s1;
        buf[tid + 512] = s2;
        buf[tid + 768] = s3;
        __syncthreads();

        const int base = (chunk0 + j) * CHUNK;
        const unsigned cv_cur = cv;

        // Prefetch chunk j+1: in flight during this chunk's compute.
        if (j + 1 < NCHUNK) {
            const floatx4* nsrc = (const floatx4*)gm_val
                                  + (size_t)(chunk0 + j + 1) * CHUNK * 4;
            s0 = nsrc[tid];
            s1 = nsrc[tid + 256];
            s2 = nsrc[tid + 512];
            s3 = nsrc[tid + 768];
            if (FUSED) cv = cnt[(chunk0 + j + 1) * CHUNK + grp + 16 * oq];
        }

        #pragma unroll 2
        for (int s = 0; s < 16; ++s) {
            const int r = base + grp + 16 * s;        // this group's row
            const floatx4* rowp = buf + (grp + 16 * s) * 4;
            floatx4 a = rowp[0], b = rowp[1], c = rowp[2], d = rowp[3];
            float v[16] = {a.x,a.y,a.z,a.w, b.x,b.y,b.z,b.w,
                           c.x,c.y,c.z,c.w, d.x,d.y,d.z,d.w};

            float t0 = 0.f, t1 = 0.f, t2 = 0.f, t3 = 0.f;
            #pragma unroll
            for (int k = 0; k < EMB; ++k) {
                t0 += v[k] * w[0][k];
                t1 += v[k] * w[1][k];
                t2 += v[k] * w[2][k];
                t3 += v[k] * w[3][k];
            }
            floatx4 o = {t0, t1, t2, t3};

            if (FUSED) {
                unsigned cR = __shfl(cv_cur, s, 16);  // cnt for this row
                if (cR) {
                    unsigned nE = cR < SLOT_CAP ? cR : SLOT_CAP;
                    for (unsigned i = 0; i < nE; ++i) {
                        unsigned e = slots[(size_t)r * SLOT_CAP + i];
                        o += *(const floatx4*)(edge_attr + (size_t)e * OUTF + oq * 4);
                    }
                }
            }
            *(floatx4*)(out_val + (size_t)r * OUTF + oq * 4) = o;
        }
        // no second barrier: double buffer + barrier(j+1) protects buf reuse
    }
}

// ---------------------------------------------------------------------------
// Fallback (workspace too small): atomic scatter + idx.
#define SCATTER_BLOCKS ((EREAL * OUTF) / 256)   // 16384
#define IDX_BLOCKS (TOTAL / 256)                // 4096

__global__ __launch_bounds__(256) void scatter_idx_kernel(
    const int* __restrict__ edge_index,
    const float* __restrict__ edge_attr,
    float* __restrict__ out_val,
    float* __restrict__ out_idx)
{
    int bid = blockIdx.x;
    if (bid < SCATTER_BLOCKS) {
        int idx = bid * 256 + threadIdx.x;
        int e = idx >> 6;
        int o = idx & 63;
        int src = edge_index[e];
        int dst = edge_index[EREAL + e];
        int fid = src * NNODE + (dst & (NNODE - 1));
        atomicAdd(out_val + (size_t)fid * OUTF + o, edge_attr[(size_t)e * OUTF + o]);
    } else {
        int p = (bid - SCATTER_BLOCKS) * 256 + threadIdx.x;
        int g   = p >> 14;
        int rem = p & 16383;
        out_idx[p]         = (float)(g * NNODE + (rem >> 7));
        out_idx[TOTAL + p] = (float)(g * NNODE + (rem & 127));
    }
}

extern "C" void kernel_launch(void* const* d_in, const int* in_sizes, int n_in,
                              void* d_out, int out_size, void* d_ws, size_t ws_size,
                              hipStream_t stream)
{
    // inputs (setup_inputs order): batch, edge_index, edge_attr, gm_index, gm_val, W
    const int*   edge_index = (const int*)d_in[1];
    const float* edge_attr  = (const float*)d_in[2];
    const float* gm_val     = (const float*)d_in[4];
    const float* W          = (const float*)d_in[5];

    float* out      = (float*)d_out;
    float* out_idx  = out;                     // first 2*TOTAL elements
    float* out_val  = out + (size_t)2 * TOTAL; // then TOTAL*OUTF elements

    const size_t ws_need = (size_t)TOTAL * 4 + (size_t)TOTAL * SLOT_CAP * 4; // 36 MiB

    if (ws_size >= ws_need) {
        unsigned* cnt   = (unsigned*)d_ws;          // [TOTAL]
        unsigned* slots = cnt + TOTAL;              // [TOTAL * SLOT_CAP]
        // A) zero counters + index output (TOTAL/4 threads)
        init_kernel<<<TOTAL / 4 / 256, 256, 0, stream>>>((uint4*)cnt, out_idx);
        // B) bin edges by pair id
        bin_kernel<<<EREAL / 256, 256, 0, stream>>>(edge_index, cnt, slots);
        // C) fused persistent double-buffered projection + edge gather
        gemm_lds_kernel<true><<<NBLOCKS, 256, 0, stream>>>(
            gm_val, W, cnt, slots, edge_attr, out_val);
    } else {
        gemm_lds_kernel<false><<<NBLOCKS, 256, 0, stream>>>(
            gm_val, W, nullptr, nullptr, nullptr, out_val);
        scatter_idx_kernel<<<SCATTER_BLOCKS + IDX_BLOCKS, 256, 0, stream>>>(
            edge_index, edge_attr, out_val, out_idx);
    }
}

// Round 7
// 356.787 us; speedup vs baseline: 1.0990x; 1.0990x over previous
//
#include <hip/hip_runtime.h>

// Problem constants (match reference)
#define BGRAPH 64
#define NNODE  128
#define EMB    16
#define OUTF   64
#define EREAL  65536
#define TOTAL  (BGRAPH * NNODE * NNODE)   // 1048576 pairs
#define EPG    (EREAL / BGRAPH)           // 1024 edges per graph, CONTIGUOUS slice

// Native clang vector type.
typedef float floatx4 __attribute__((ext_vector_type(4)));

#define SLOT_CAP 8
#define CHUNK 256
#define NBLOCKS (TOTAL / CHUNK)   // 4096 blocks, one 256-row chunk each

// ---------------------------------------------------------------------------
// Single fused kernel. Per block (chunk = 256 output rows = 2 src nodes of
// graph g = blockIdx>>6):
//   1. issue gm_val stage loads (16 KB dense)
//   2. issue this graph's edge slice loads (8 KB int4, L3-resident)
//   3. write idx output for this chunk (no load dependence — overlaps latency)
//   4. load W (4 KB, L2 broadcast) into registers
//   5. zero LDS edge-bin counters; ds_write the gm stage; barrier
//   6. scan 1024 edges, LDS-bin the ~16 that land in this chunk
//      (fid>>8 == blockIdx); barrier
//   7. 16-step compute: LDS row broadcast -> 64 FMA -> LDS-binned edge
//      gather -> NT store (1 KB contiguous per wave-instr)
//
// This is round-5's measured-best gemm core (4096 blocks, single-buffer LDS,
// NT stores) with init/bin kernels + their global traffic folded away.
__global__ __launch_bounds__(256) void fused_kernel(
    const float* __restrict__ gm_val,
    const float* __restrict__ W,
    const int* __restrict__ edge_index,   // [2, EREAL] flat: src then dst
    const float* __restrict__ edge_attr,  // [EREAL, OUTF]
    float* __restrict__ out_val,
    float* __restrict__ out_idx)
{
    __shared__ floatx4  stage[CHUNK * 4];            // 16 KB
    __shared__ unsigned lcnt[CHUNK];                 // 1 KB
    __shared__ unsigned lslot[CHUNK * SLOT_CAP];     // 8 KB

    const int tid  = threadIdx.x;
    const int oq   = tid & 15;                       // lane within group
    const int grp  = tid >> 4;                       // 0..15
    const int base = blockIdx.x * CHUNK;
    const int g    = base >> 14;                     // graph id (= blockIdx>>6)

    // 1) gm stage loads: 4 dense float4 per thread.
    const floatx4* src = (const floatx4*)gm_val + (size_t)base * 4;
    floatx4 s0 = src[tid];
    floatx4 s1 = src[tid + 256];
    floatx4 s2 = src[tid + 512];
    floatx4 s3 = src[tid + 768];

    // 2) edge slice loads: graph g's 1024 src + 1024 dst ints, one int4 each.
    int4 e4s = ((const int4*)(edge_index + g * EPG))[tid];
    int4 e4d = ((const int4*)(edge_index + EREAL + g * EPG))[tid];

    // 3) idx output for this chunk (2 KB, coalesced; independent of loads).
    {
        int p = base + tid;
        out_idx[p]         = (float)(g * NNODE + ((p >> 7) & (NNODE - 1)));
        out_idx[TOTAL + p] = (float)(g * NNODE + (p & (NNODE - 1)));
    }

    // 4) W slice for this lane's output quad (64 floats, L2 broadcast).
    float w[4][16];
    const floatx4* W4 = (const floatx4*)W + oq * 16;
    #pragma unroll
    for (int j = 0; j < 4; ++j) {
        #pragma unroll
        for (int q = 0; q < 4; ++q) {
            floatx4 t = W4[j * 4 + q];
            w[j][q * 4 + 0] = t.x;
            w[j][q * 4 + 1] = t.y;
            w[j][q * 4 + 2] = t.z;
            w[j][q * 4 + 3] = t.w;
        }
    }

    // 5) zero bin counters (tid covers CHUNK exactly) and stage gm chunk.
    lcnt[tid] = 0u;
    stage[tid]       = s0;
    stage[tid + 256] = s1;
    stage[tid + 512] = s2;
    stage[tid + 768] = s3;
    __syncthreads();

    // 6) bin matching edges: fid = src_global*128 + dst_local;
    //    fid>>8 == blockIdx  <=>  fid in [base, base+256).
    #pragma unroll
    for (int i = 0; i < 4; ++i) {
        int es = (i == 0) ? e4s.x : (i == 1) ? e4s.y : (i == 2) ? e4s.z : e4s.w;
        int ed = (i == 0) ? e4d.x : (i == 1) ? e4d.y : (i == 2) ? e4d.z : e4d.w;
        int fid = es * NNODE + (ed & (NNODE - 1));
        if ((fid >> 8) == (int)blockIdx.x) {
            unsigned lr  = (unsigned)(fid & (CHUNK - 1));
            unsigned pos = atomicAdd(&lcnt[lr], 1u);
            if (pos < SLOT_CAP)
                lslot[lr * SLOT_CAP + pos] = (unsigned)(tid * 4 + i); // local id
        }
    }
    __syncthreads();

    // 7) compute: group grp, step s handles local row grp + 16*s. A wave's
    //    4 groups cover 4 consecutive rows -> each NT store writes 1 KB
    //    contiguous. Row read from LDS is uniform-address (broadcast).
    for (int s = 0; s < 16; ++s) {
        const int lr = grp + 16 * s;
        const int r  = base + lr;
        const floatx4* rowp = stage + lr * 4;
        floatx4 a = rowp[0], b = rowp[1], c = rowp[2], d = rowp[3];
        float v[16] = {a.x,a.y,a.z,a.w, b.x,b.y,b.z,b.w,
                       c.x,c.y,c.z,c.w, d.x,d.y,d.z,d.w};

        float t0 = 0.f, t1 = 0.f, t2 = 0.f, t3 = 0.f;
        #pragma unroll
        for (int k = 0; k < EMB; ++k) {
            t0 += v[k] * w[0][k];
            t1 += v[k] * w[1][k];
            t2 += v[k] * w[2][k];
            t3 += v[k] * w[3][k];
        }
        floatx4 o = {t0, t1, t2, t3};

        unsigned cR = lcnt[lr];                       // LDS broadcast
        if (cR) {
            unsigned nE = cR < SLOT_CAP ? cR : SLOT_CAP;
            for (unsigned i = 0; i < nE; ++i) {
                unsigned e = (unsigned)(g * EPG) + lslot[lr * SLOT_CAP + i];
                o += *(const floatx4*)(edge_attr + (size_t)e * OUTF + oq * 4);
            }
        }
        __builtin_nontemporal_store(o, (floatx4*)(out_val + (size_t)r * OUTF + oq * 4));
    }
}

extern "C" void kernel_launch(void* const* d_in, const int* in_sizes, int n_in,
                              void* d_out, int out_size, void* d_ws, size_t ws_size,
                              hipStream_t stream)
{
    // inputs (setup_inputs order): batch, edge_index, edge_attr, gm_index, gm_val, W
    const int*   edge_index = (const int*)d_in[1];
    const float* edge_attr  = (const float*)d_in[2];
    const float* gm_val     = (const float*)d_in[4];
    const float* W          = (const float*)d_in[5];

    float* out      = (float*)d_out;
    float* out_idx  = out;                     // first 2*TOTAL elements
    float* out_val  = out + (size_t)2 * TOTAL; // then TOTAL*OUTF elements

    // Single launch: projection + per-block LDS edge binning + gather + idx.
    fused_kernel<<<NBLOCKS, 256, 0, stream>>>(
        gm_val, W, edge_index, edge_attr, out_val, out_idx);
}